// Round 1
// baseline (243.905 us; speedup 1.0000x reference)
//
#include <hip/hip_runtime.h>
#include <hip/hip_bf16.h>

#define N_NODES 25000
#define N_EDGES 100000
#define E_PAD   100032   // 1563 * 64

typedef __attribute__((ext_vector_type(8))) short bf16x8;
typedef __attribute__((ext_vector_type(4))) float f32x4;

__device__ __forceinline__ void gload_lds16(const void* g, void* l) {
  __builtin_amdgcn_global_load_lds(
      (const __attribute__((address_space(1))) unsigned int*)g,
      (__attribute__((address_space(3))) unsigned int*)l, 16, 0, 0);
}

__device__ __forceinline__ unsigned short f2bf(float v) {
  __hip_bfloat16 hb = __float2bfloat16(v);
  return *reinterpret_cast<unsigned short*>(&hb);
}

__device__ __forceinline__ unsigned fkey(float f) {
  unsigned u = __float_as_uint(f);
  return (u & 0x80000000u) ? ~u : (u | 0x80000000u);
}
__device__ __forceinline__ float fdec(unsigned k) {
  return (k & 0x80000000u) ? __uint_as_float(k ^ 0x80000000u) : __uint_as_float(~k);
}

// h = relu(e @ W1 + b1), stored bf16 with per-row XOR swizzle (byte ^= (e&7)<<4)
__global__ __launch_bounds__(256) void k_h(const float* __restrict__ ef,
    const float* __restrict__ W1, const float* __restrict__ b1,
    unsigned char* __restrict__ hout) {
  int g = blockIdx.x * 256 + threadIdx.x;          // E_PAD*128 threads
  int e = g >> 7, k = g & 127;
  float acc = 0.f;
  if (e < N_EDGES) {
    acc = b1[k];
    const float* er = ef + (size_t)e * 16;
    #pragma unroll
    for (int j = 0; j < 16; ++j) acc += er[j] * W1[j * 128 + k];
    acc = acc > 0.f ? acc : 0.f;
  }
  *(unsigned short*)(hout + (size_t)e * 256 + (((unsigned)(k * 2)) ^ ((e & 7) << 4))) = f2bf(acc);
}

// W2 -> bf16, layout [i=V_IN chunk][o=0..63][k=0..127], row-swizzled on o
__global__ __launch_bounds__(256) void k_w2bt(const float* __restrict__ W2,
    unsigned char* __restrict__ out) {
  int g = blockIdx.x * 256 + threadIdx.x;          // 262144 threads
  int k = g >> 11, col = g & 2047;
  int i = col >> 6, o = col & 63;
  *(unsigned short*)(out + (size_t)i * 16384 + o * 256 +
                     (((unsigned)(k * 2)) ^ ((o & 7) << 4))) = f2bf(W2[g]);
}

// xb[n,o] = sum_i x[n,i] * b2[i*64+o]  (b2's contribution to xi/xj)
__global__ __launch_bounds__(256) void k_xb(const float* __restrict__ x,
    const float* __restrict__ b2, float* __restrict__ xb) {
  int g = blockIdx.x * 256 + threadIdx.x;          // N*64
  int n = g >> 6, o = g & 63;
  const float* xr = x + (size_t)n * 32;
  float acc = 0.f;
  #pragma unroll
  for (int i = 0; i < 32; ++i) acc += xr[i] * b2[i * 64 + o];
  xb[g] = acc;
}

// ab1[n,h] = xb[n]·att1[h],  ab2[n,h] = xb[n]·att2[h]
__global__ __launch_bounds__(256) void k_ab(const float* __restrict__ xb,
    const float* __restrict__ att, float* __restrict__ ab1, float* __restrict__ ab2) {
  int g = blockIdx.x * 256 + threadIdx.x;
  if (g >= N_NODES * 8) return;
  int n = g >> 3, hd = g & 7;
  const float* xr = xb + (size_t)n * 64 + hd * 8;
  float s1 = 0.f, s2 = 0.f;
  #pragma unroll
  for (int c = 0; c < 8; ++c) {
    s1 += xr[c] * att[hd * 16 + c];
    s2 += xr[c] * att[hd * 16 + 8 + c];
  }
  ab1[g] = s1; ab2[g] = s2;
}

__global__ __launch_bounds__(256) void k_init(unsigned* __restrict__ mk, float* __restrict__ s) {
  int g = blockIdx.x * 256 + threadIdx.x;
  if (g >= N_NODES * 8) return;
  mk[g] = 0u; s[g] = 0.f;
}

// Fused: per 64-edge tile, for each i in 0..31: G = h_tile @ W2[:, i*64:+64] (MFMA),
// xj += x_src[:,i]*G, xi += x_dst[:,i]*G.  Then attention logits + leaky_relu.
__global__ __launch_bounds__(256) void k_main(
    const float* __restrict__ x, const int* __restrict__ ei,
    const float* __restrict__ att, const float* __restrict__ ab1,
    const float* __restrict__ ab2, const unsigned char* __restrict__ hbf,
    const unsigned char* __restrict__ w2bt,
    float* __restrict__ xj_out, float* __restrict__ alpha_out) {
  __shared__ unsigned char smem[65536];
  unsigned char* lds_h = smem;                 // 16 KB  swizzled h tile [64][128]bf16
  unsigned char* lds_b = smem + 16384;         // 2x16 KB swizzled W2 chunk [64][128]bf16
  float* lds_xs = (float*)(smem + 49152);      // [32][64] x[src] transposed
  float* lds_xd = (float*)(smem + 57344);      // [32][64] x[dst] transposed
  const int tid = threadIdx.x;
  const int lane = tid & 63;
  const int w = tid >> 6;                      // wave id: owns output cols w*16..+15
  const int e0 = blockIdx.x * 64;
  const int* srcp = ei;
  const int* dstp = ei + N_EDGES;

  // stage h tile + B chunk 0 (linear dest; sources pre-swizzled in ws)
  const unsigned char* hg = hbf + (size_t)e0 * 256;
  #pragma unroll
  for (int r = 0; r < 4; ++r)
    gload_lds16(hg + w * 4096 + r * 1024 + lane * 16, lds_h + w * 4096 + r * 1024);
  #pragma unroll
  for (int r = 0; r < 4; ++r)
    gload_lds16(w2bt + w * 4096 + r * 1024 + lane * 16, lds_b + w * 4096 + r * 1024);

  // gather x rows for src/dst (transposed into LDS)
  {
    int m = tid & 63;
    int half = (tid >> 6) & 1;
    int which = tid >> 7;
    int eIdx = e0 + m; if (eIdx >= N_EDGES) eIdx = N_EDGES - 1;
    int node = which ? dstp[eIdx] : srcp[eIdx];
    const f32x4* xr = (const f32x4*)(x + (size_t)node * 32 + half * 16);
    float* lx = which ? lds_xd : lds_xs;
    #pragma unroll
    for (int q = 0; q < 4; ++q) {
      f32x4 v = xr[q];
      int i0 = half * 16 + q * 4;
      #pragma unroll
      for (int j = 0; j < 4; ++j) lx[(i0 + j) * 64 + m] = v[j];
    }
  }
  __syncthreads();

  // A fragments hoisted (i-invariant): rows = all 64 edges, K=128
  const int lrow = lane & 15;
  const int lkb = (lane >> 4) << 4;            // k byte offset within row
  bf16x8 af[4][4];
  #pragma unroll
  for (int mt = 0; mt < 4; ++mt) {
    int row = mt * 16 + lrow;
    int sw = (row & 7) << 4;
    #pragma unroll
    for (int s = 0; s < 4; ++s)
      af[mt][s] = *(const bf16x8*)(lds_h + row * 256 + ((s * 64 + lkb) ^ sw));
  }
  const int orow = w * 16 + lrow;
  const int bsw = (orow & 7) << 4;
  int boff[4];
  #pragma unroll
  for (int s = 0; s < 4; ++s) boff[s] = orow * 256 + ((s * 64 + lkb) ^ bsw);

  f32x4 xj_acc[4] = {};
  f32x4 xi_acc[4] = {};
  const int rg4 = ((lane >> 4) & 3) * 4;

  for (int i = 0; i < 32; ++i) {
    const unsigned char* bb = lds_b + (size_t)(i & 1) * 16384;
    if (i < 31) {   // prefetch next W2 chunk into other buffer
      const unsigned char* wg = w2bt + (size_t)(i + 1) * 16384;
      unsigned char* lb = lds_b + (size_t)((i + 1) & 1) * 16384;
      #pragma unroll
      for (int r = 0; r < 4; ++r)
        gload_lds16(wg + w * 4096 + r * 1024 + lane * 16, lb + w * 4096 + r * 1024);
    }
    bf16x8 bfr[4];
    #pragma unroll
    for (int s = 0; s < 4; ++s) bfr[s] = *(const bf16x8*)(bb + boff[s]);
    #pragma unroll
    for (int mt = 0; mt < 4; ++mt) {
      f32x4 g = {0.f, 0.f, 0.f, 0.f};
      #pragma unroll
      for (int s = 0; s < 4; ++s)
        g = __builtin_amdgcn_mfma_f32_16x16x32_bf16(af[mt][s], bfr[s], g, 0, 0, 0);
      f32x4 xsv = *(const f32x4*)(lds_xs + i * 64 + mt * 16 + rg4);
      f32x4 xdv = *(const f32x4*)(lds_xd + i * 64 + mt * 16 + rg4);
      #pragma unroll
      for (int r = 0; r < 4; ++r) {
        xj_acc[mt][r] += xsv[r] * g[r];
        xi_acc[mt][r] += xdv[r] * g[r];
      }
    }
    __syncthreads();
  }

  // epilogue: store xj, compute attention logits (reduce over 8 channels/head)
  const int h2 = (lane >> 3) & 1;
  const int cc = lane & 7;
  const int head = 2 * w + h2;
  const float a1v = att[head * 16 + cc];
  const float a2v = att[head * 16 + 8 + cc];
  #pragma unroll
  for (int mt = 0; mt < 4; ++mt) {
    #pragma unroll
    for (int r = 0; r < 4; ++r) {
      int row = mt * 16 + rg4 + r;
      xj_out[(size_t)(e0 + row) * 64 + w * 16 + (lane & 15)] = xj_acc[mt][r];
      float v = xi_acc[mt][r] * a1v + xj_acc[mt][r] * a2v;
      v += __shfl_xor(v, 1);
      v += __shfl_xor(v, 2);
      v += __shfl_xor(v, 4);
      if (cc == 0) {
        int eIdx = e0 + row;
        int ec = eIdx < N_EDGES ? eIdx : N_EDGES - 1;
        float lg = v + ab1[(size_t)dstp[ec] * 8 + head] + ab2[(size_t)srcp[ec] * 8 + head];
        lg = lg > 0.f ? lg : 0.2f * lg;
        alpha_out[(size_t)eIdx * 8 + head] = lg;
      }
    }
  }
}

__global__ __launch_bounds__(256) void k_max(const float* __restrict__ alpha,
    const int* __restrict__ ei, unsigned* __restrict__ mk) {
  int g = blockIdx.x * 256 + threadIdx.x;          // E*8 exact
  int e = g >> 3, hd = g & 7;
  int d = ei[N_EDGES + e];
  atomicMax(mk + (size_t)d * 8 + hd, fkey(alpha[g]));
}

__global__ __launch_bounds__(256) void k_exp(float* __restrict__ alpha,
    const int* __restrict__ ei, const unsigned* __restrict__ mk, float* __restrict__ s) {
  int g = blockIdx.x * 256 + threadIdx.x;          // E*8 exact
  int e = g >> 3, hd = g & 7;
  int d = ei[N_EDGES + e];
  float ea = expf(alpha[g] - fdec(mk[(size_t)d * 8 + hd]));
  alpha[g] = ea;
  atomicAdd(s + (size_t)d * 8 + hd, ea);
}

__global__ __launch_bounds__(256) void k_root(const float* __restrict__ x,
    const float* __restrict__ root, const float* __restrict__ bias, float* __restrict__ out) {
  int g = blockIdx.x * 256 + threadIdx.x;          // N*64 exact
  int n = g >> 6, o = g & 63;
  const float* xr = x + (size_t)n * 32;
  float acc = bias[o];
  #pragma unroll
  for (int i = 0; i < 32; ++i) acc += xr[i] * root[i * 64 + o];
  out[g] = acc;
}

__global__ __launch_bounds__(256) void k_scatter(const float* __restrict__ xj,
    const float* __restrict__ xb, const float* __restrict__ alpha,
    const float* __restrict__ s, const int* __restrict__ ei,
    const float* __restrict__ bias, float* __restrict__ out) {
  int g = blockIdx.x * 256 + threadIdx.x;          // E*64 exact
  int e = g >> 6, o = g & 63, hd = o >> 3;
  int sidx = ei[e], d = ei[N_EDGES + e];
  float ea = alpha[(size_t)e * 8 + hd];
  float sv = s[(size_t)d * 8 + hd];
  float val = (xj[g] + xb[(size_t)sidx * 64 + o]) * (ea / (sv + 1e-16f)) + bias[o];
  atomicAdd(out + (size_t)d * 64 + o, val);
}

__global__ __launch_bounds__(256) void k_elu(float* __restrict__ out) {
  int g = blockIdx.x * 256 + threadIdx.x;          // N*64 exact
  float v = out[g];
  out[g] = v > 0.f ? v : expm1f(v);
}

extern "C" void kernel_launch(void* const* d_in, const int* in_sizes, int n_in,
                              void* d_out, int out_size, void* d_ws, size_t ws_size,
                              hipStream_t stream) {
  const float* x    = (const float*)d_in[0];
  const int*   eidx = (const int*)d_in[1];
  const float* ef   = (const float*)d_in[2];
  const float* W1   = (const float*)d_in[3];
  const float* b1   = (const float*)d_in[4];
  const float* W2   = (const float*)d_in[5];
  const float* b2   = (const float*)d_in[6];
  const float* att  = (const float*)d_in[7];
  const float* bias = (const float*)d_in[8];
  const float* root = (const float*)d_in[9];
  float* out = (float*)d_out;
  char* ws = (char*)d_ws;

  // workspace layout (all 256B aligned), total ~64.5 MB
  unsigned char* h_bf  = (unsigned char*)(ws + 0);          // E_PAD*128 bf16 = 25,608,192
  unsigned char* w2bt  = (unsigned char*)(ws + 25608192);   // 512 KB
  float* xb    = (float*)(ws + 26132480);                   // N*64 f32
  float* ab1   = (float*)(ws + 32532480);                   // N*8 f32
  float* ab2   = (float*)(ws + 33332480);                   // N*8 f32
  float* xj_ws = (float*)(ws + 34132480);                   // E_PAD*64 f32
  float* al_ws = (float*)(ws + 59740672);                   // E_PAD*8 f32
  unsigned* mk = (unsigned*)(ws + 62941696);                // N*8 u32
  float* s_sum = (float*)(ws + 63741696);                   // N*8 f32

  k_h    <<<E_PAD * 128 / 256, 256, 0, stream>>>(ef, W1, b1, h_bf);
  k_w2bt <<<1024, 256, 0, stream>>>(W2, w2bt);
  k_xb   <<<N_NODES * 64 / 256, 256, 0, stream>>>(x, b2, xb);
  k_ab   <<<(N_NODES * 8 + 255) / 256, 256, 0, stream>>>(xb, att, ab1, ab2);
  k_init <<<(N_NODES * 8 + 255) / 256, 256, 0, stream>>>(mk, s_sum);
  k_main <<<E_PAD / 64, 256, 0, stream>>>(x, eidx, att, ab1, ab2, h_bf, w2bt, xj_ws, al_ws);
  k_max  <<<N_EDGES * 8 / 256, 256, 0, stream>>>(al_ws, eidx, mk);
  k_exp  <<<N_EDGES * 8 / 256, 256, 0, stream>>>(al_ws, eidx, mk, s_sum);
  k_root <<<N_NODES * 64 / 256, 256, 0, stream>>>(x, root, bias, out);
  k_scatter<<<N_EDGES * 64 / 256, 256, 0, stream>>>(xj_ws, xb, al_ws, s_sum, eidx, bias, out);
  k_elu  <<<N_NODES * 64 / 256, 256, 0, stream>>>(out);
}

// Round 3
// 229.965 us; speedup vs baseline: 1.0606x; 1.0606x over previous
//
#include <hip/hip_runtime.h>
#include <hip/hip_bf16.h>

#define N_NODES 25000
#define N_EDGES 100000
#define E_PAD   100032   // 1563 * 64

typedef __attribute__((ext_vector_type(8))) short bf16x8;
typedef __attribute__((ext_vector_type(4))) float f32x4;

__device__ __forceinline__ void gload_lds16(const void* g, void* l) {
  __builtin_amdgcn_global_load_lds(
      (const __attribute__((address_space(1))) unsigned int*)g,
      (__attribute__((address_space(3))) unsigned int*)l, 16, 0, 0);
}

__device__ __forceinline__ unsigned short f2bf(float v) {
  __hip_bfloat16 hb = __float2bfloat16(v);
  return *reinterpret_cast<unsigned short*>(&hb);
}

__device__ __forceinline__ unsigned fkey(float f) {
  unsigned u = __float_as_uint(f);
  return (u & 0x80000000u) ? ~u : (u | 0x80000000u);
}
__device__ __forceinline__ float fdec(unsigned k) {
  return (k & 0x80000000u) ? __uint_as_float(k ^ 0x80000000u) : __uint_as_float(~k);
}

// h = relu(e @ W1 + b1), bf16, per-row XOR swizzle (byte ^= (e&7)<<4).
// One thread per 8 outputs -> one coalesced 16B store.
__global__ __launch_bounds__(256) void k_h(const float* __restrict__ ef,
    const float* __restrict__ W1, const float* __restrict__ b1,
    unsigned char* __restrict__ hout) {
  int g = blockIdx.x * 256 + threadIdx.x;          // E_PAD*16 threads
  int e = g >> 4, kc = g & 15;
  int k0 = kc * 8;
  bf16x8 v;
  if (e < N_EDGES) {
    f32x4 acc0 = *(const f32x4*)(b1 + k0);
    f32x4 acc1 = *(const f32x4*)(b1 + k0 + 4);
    const float* er = ef + (size_t)e * 16;
    #pragma unroll
    for (int j = 0; j < 16; ++j) {
      float ev = er[j];
      f32x4 w0 = *(const f32x4*)(W1 + j * 128 + k0);
      f32x4 w1 = *(const f32x4*)(W1 + j * 128 + k0 + 4);
      #pragma unroll
      for (int r = 0; r < 4; ++r) { acc0[r] += ev * w0[r]; acc1[r] += ev * w1[r]; }
    }
    #pragma unroll
    for (int r = 0; r < 4; ++r) {
      v[r]     = (short)f2bf(acc0[r] > 0.f ? acc0[r] : 0.f);
      v[r + 4] = (short)f2bf(acc1[r] > 0.f ? acc1[r] : 0.f);
    }
  } else {
    #pragma unroll
    for (int r = 0; r < 8; ++r) v[r] = 0;
  }
  *(bf16x8*)(hout + (size_t)e * 256 + (((unsigned)(k0 * 2)) ^ ((e & 7) << 4))) = v;
}

// W2 -> bf16 packed in per-(chunk i, wave w, lane, s) MFMA B-fragment order:
// 16B frag at ((i*4+w)*64+lane)*64 + s*16 holds W2[k0..k0+8][i*64 + w*16 + (lane&15)]
// with k0 = s*32 + (lane>>4)*8.
__global__ __launch_bounds__(256) void k_w2pk(const float* __restrict__ W2,
    unsigned char* __restrict__ out) {
  int g = blockIdx.x * 256 + threadIdx.x;          // 32768 threads
  int s = g & 3, lane = (g >> 2) & 63, w = (g >> 8) & 3, i = g >> 10;
  int col = i * 64 + w * 16 + (lane & 15);
  int k0 = s * 32 + (lane >> 4) * 8;
  bf16x8 v;
  #pragma unroll
  for (int j = 0; j < 8; ++j)
    v[j] = (short)f2bf(W2[(size_t)(k0 + j) * 2048 + col]);
  *(bf16x8*)(out + (size_t)g * 16) = v;
}

// xb[n,o] = sum_i x[n,i] * b2[i*64+o]  (b2's contribution to xi/xj)
__global__ __launch_bounds__(256) void k_xb(const float* __restrict__ x,
    const float* __restrict__ b2, float* __restrict__ xb) {
  int g = blockIdx.x * 256 + threadIdx.x;          // N*64
  int n = g >> 6, o = g & 63;
  const float* xr = x + (size_t)n * 32;
  float acc = 0.f;
  #pragma unroll
  for (int i = 0; i < 32; ++i) acc += xr[i] * b2[i * 64 + o];
  xb[g] = acc;
}

// ab1[n,h] = xb[n]·att1[h],  ab2[n,h] = xb[n]·att2[h]
__global__ __launch_bounds__(256) void k_ab(const float* __restrict__ xb,
    const float* __restrict__ att, float* __restrict__ ab1, float* __restrict__ ab2) {
  int g = blockIdx.x * 256 + threadIdx.x;
  if (g >= N_NODES * 8) return;
  int n = g >> 3, hd = g & 7;
  const float* xr = xb + (size_t)n * 64 + hd * 8;
  float s1 = 0.f, s2 = 0.f;
  #pragma unroll
  for (int c = 0; c < 8; ++c) {
    s1 += xr[c] * att[hd * 16 + c];
    s2 += xr[c] * att[hd * 16 + 8 + c];
  }
  ab1[g] = s1; ab2[g] = s2;
}

__global__ __launch_bounds__(256) void k_init(unsigned* __restrict__ mk, float* __restrict__ s) {
  int g = blockIdx.x * 256 + threadIdx.x;
  if (g >= N_NODES * 8) return;
  mk[g] = 0u; s[g] = 0.f;
}

// Fused per-64-edge tile: for i in 0..31: G = h_tile @ W2[:,i*64:+64] (MFMA, B from
// global in packed fragment order, double-buffered in regs, NO barriers in loop),
// xj += x_src[:,i]*G, xi += x_dst[:,i]*G. Epilogue: attention logits + atomicMax.
__global__ __launch_bounds__(256, 3) void k_main(
    const float* __restrict__ x, const int* __restrict__ ei,
    const float* __restrict__ att, const float* __restrict__ ab1,
    const float* __restrict__ ab2, const unsigned char* __restrict__ hbf,
    const unsigned char* __restrict__ w2pk,
    float* __restrict__ xj_out, float* __restrict__ alpha_out,
    unsigned* __restrict__ mk) {
  __shared__ unsigned char smem[32768];
  unsigned char* lds_h = smem;                 // 16 KB swizzled h tile [64 rows][128]bf16
  float* lds_xs = (float*)(smem + 16384);      // [32][64] x[src] transposed
  float* lds_xd = (float*)(smem + 24576);      // [32][64] x[dst] transposed
  const int tid = threadIdx.x;
  const int lane = tid & 63;
  const int w = tid >> 6;                      // wave id: owns output cols w*16..+15
  const int e0 = blockIdx.x * 64;
  const int* srcp = ei;
  const int* dstp = ei + N_EDGES;

  // stage h tile (linear dest; source pre-swizzled in ws)
  const unsigned char* hg = hbf + (size_t)e0 * 256;
  #pragma unroll
  for (int r = 0; r < 4; ++r)
    gload_lds16(hg + w * 4096 + r * 1024 + lane * 16, lds_h + w * 4096 + r * 1024);

  // gather x rows for src/dst (transposed into LDS)
  {
    int m = tid & 63;
    int half = (tid >> 6) & 1;
    int which = tid >> 7;
    int eIdx = e0 + m; if (eIdx >= N_EDGES) eIdx = N_EDGES - 1;
    int node = which ? dstp[eIdx] : srcp[eIdx];
    const f32x4* xr = (const f32x4*)(x + (size_t)node * 32 + half * 16);
    float* lx = which ? lds_xd : lds_xs;
    #pragma unroll
    for (int q = 0; q < 4; ++q) {
      f32x4 vv = xr[q];
      int i0 = half * 16 + q * 4;
      #pragma unroll
      for (int j = 0; j < 4; ++j) lx[(i0 + j) * 64 + m] = vv[j];
    }
  }
  __syncthreads();

  // A fragments (i-invariant): rows = all 64 edges, K=128
  const int lrow = lane & 15;
  const int lkb = (lane >> 4) << 4;            // k byte offset within row
  bf16x8 af[4][4];
  #pragma unroll
  for (int mt = 0; mt < 4; ++mt) {
    int row = mt * 16 + lrow;
    int sw = (row & 7) << 4;
    #pragma unroll
    for (int s = 0; s < 4; ++s)
      af[mt][s] = *(const bf16x8*)(lds_h + row * 256 + ((s * 64 + lkb) ^ sw));
  }

  // B fragments straight from global (L2-resident), register double-buffer
  const unsigned char* bgp = w2pk + (size_t)w * 4096 + (size_t)lane * 64;
  bf16x8 bA[4], bB[4];
  #pragma unroll
  for (int s = 0; s < 4; ++s) bA[s] = *(const bf16x8*)(bgp + s * 16);

  f32x4 xj_acc[4] = {};
  f32x4 xi_acc[4] = {};
  const int rg4 = ((lane >> 4) & 3) * 4;

  #pragma unroll 1
  for (int i = 0; i < 32; i += 2) {
    // prefetch chunk i+1 into bB
    #pragma unroll
    for (int s = 0; s < 4; ++s)
      bB[s] = *(const bf16x8*)(bgp + (size_t)(i + 1) * 16384 + s * 16);
    // compute chunk i from bA
    #pragma unroll
    for (int mt = 0; mt < 4; ++mt) {
      f32x4 g = {0.f, 0.f, 0.f, 0.f};
      #pragma unroll
      for (int s = 0; s < 4; ++s)
        g = __builtin_amdgcn_mfma_f32_16x16x32_bf16(af[mt][s], bA[s], g, 0, 0, 0);
      f32x4 xsv = *(const f32x4*)(lds_xs + i * 64 + mt * 16 + rg4);
      f32x4 xdv = *(const f32x4*)(lds_xd + i * 64 + mt * 16 + rg4);
      #pragma unroll
      for (int r = 0; r < 4; ++r) {
        xj_acc[mt][r] += xsv[r] * g[r];
        xi_acc[mt][r] += xdv[r] * g[r];
      }
    }
    // prefetch chunk i+2 into bA (wraps harmlessly on last iter)
    {
      int inx = (i + 2) & 31;
      #pragma unroll
      for (int s = 0; s < 4; ++s)
        bA[s] = *(const bf16x8*)(bgp + (size_t)inx * 16384 + s * 16);
    }
    // compute chunk i+1 from bB
    #pragma unroll
    for (int mt = 0; mt < 4; ++mt) {
      f32x4 g = {0.f, 0.f, 0.f, 0.f};
      #pragma unroll
      for (int s = 0; s < 4; ++s)
        g = __builtin_amdgcn_mfma_f32_16x16x32_bf16(af[mt][s], bB[s], g, 0, 0, 0);
      f32x4 xsv = *(const f32x4*)(lds_xs + (i + 1) * 64 + mt * 16 + rg4);
      f32x4 xdv = *(const f32x4*)(lds_xd + (i + 1) * 64 + mt * 16 + rg4);
      #pragma unroll
      for (int r = 0; r < 4; ++r) {
        xj_acc[mt][r] += xsv[r] * g[r];
        xi_acc[mt][r] += xdv[r] * g[r];
      }
    }
  }

  // epilogue: store xj, attention logits (reduce 8 channels/head), fused atomicMax
  const int h2 = (lane >> 3) & 1;
  const int cc = lane & 7;
  const int head = 2 * w + h2;
  const float a1v = att[head * 16 + cc];
  const float a2v = att[head * 16 + 8 + cc];
  #pragma unroll
  for (int mt = 0; mt < 4; ++mt) {
    #pragma unroll
    for (int r = 0; r < 4; ++r) {
      int row = mt * 16 + rg4 + r;
      int eIdx = e0 + row;
      xj_out[(size_t)eIdx * 64 + w * 16 + (lane & 15)] = xj_acc[mt][r];
      float v = xi_acc[mt][r] * a1v + xj_acc[mt][r] * a2v;
      v += __shfl_xor(v, 1);
      v += __shfl_xor(v, 2);
      v += __shfl_xor(v, 4);
      if (cc == 0 && eIdx < N_EDGES) {
        int d = dstp[eIdx];
        float lg = v + ab1[(size_t)d * 8 + head] + ab2[(size_t)srcp[eIdx] * 8 + head];
        lg = lg > 0.f ? lg : 0.2f * lg;
        alpha_out[(size_t)eIdx * 8 + head] = lg;
        atomicMax(mk + (size_t)d * 8 + head, fkey(lg));
      }
    }
  }
}

__global__ __launch_bounds__(256) void k_exp(float* __restrict__ alpha,
    const int* __restrict__ ei, const unsigned* __restrict__ mk, float* __restrict__ s) {
  int g = blockIdx.x * 256 + threadIdx.x;          // E*8 exact
  int e = g >> 3, hd = g & 7;
  int d = ei[N_EDGES + e];
  float ea = expf(alpha[g] - fdec(mk[(size_t)d * 8 + hd]));
  alpha[g] = ea;
  atomicAdd(s + (size_t)d * 8 + hd, ea);
}

__global__ __launch_bounds__(256) void k_root(const float* __restrict__ x,
    const float* __restrict__ root, const float* __restrict__ bias, float* __restrict__ out) {
  int g = blockIdx.x * 256 + threadIdx.x;          // N*64 exact
  int n = g >> 6, o = g & 63;
  const float* xr = x + (size_t)n * 32;
  float acc = bias[o];
  #pragma unroll
  for (int i = 0; i < 32; ++i) acc += xr[i] * root[i * 64 + o];
  out[g] = acc;
}

__global__ __launch_bounds__(256) void k_scatter(const float* __restrict__ xj,
    const float* __restrict__ xb, const float* __restrict__ alpha,
    const float* __restrict__ s, const int* __restrict__ ei,
    const float* __restrict__ bias, float* __restrict__ out) {
  int g = blockIdx.x * 256 + threadIdx.x;          // E*64 exact
  int e = g >> 6, o = g & 63, hd = o >> 3;
  int sidx = ei[e], d = ei[N_EDGES + e];
  float ea = alpha[(size_t)e * 8 + hd];
  float sv = s[(size_t)d * 8 + hd];
  float val = (xj[g] + xb[(size_t)sidx * 64 + o]) * (ea / (sv + 1e-16f)) + bias[o];
  atomicAdd(out + (size_t)d * 64 + o, val);
}

__global__ __launch_bounds__(256) void k_elu(float* __restrict__ out) {
  int g = blockIdx.x * 256 + threadIdx.x;          // N*64 exact
  float v = out[g];
  out[g] = v > 0.f ? v : expm1f(v);
}

extern "C" void kernel_launch(void* const* d_in, const int* in_sizes, int n_in,
                              void* d_out, int out_size, void* d_ws, size_t ws_size,
                              hipStream_t stream) {
  const float* x    = (const float*)d_in[0];
  const int*   eidx = (const int*)d_in[1];
  const float* ef   = (const float*)d_in[2];
  const float* W1   = (const float*)d_in[3];
  const float* b1   = (const float*)d_in[4];
  const float* W2   = (const float*)d_in[5];
  const float* b2   = (const float*)d_in[6];
  const float* att  = (const float*)d_in[7];
  const float* bias = (const float*)d_in[8];
  const float* root = (const float*)d_in[9];
  float* out = (float*)d_out;
  char* ws = (char*)d_ws;

  // workspace layout (all 256B aligned), total ~64.5 MB
  unsigned char* h_bf  = (unsigned char*)(ws + 0);          // E_PAD*128 bf16 = 25,608,192
  unsigned char* w2pk  = (unsigned char*)(ws + 25608192);   // 512 KB packed B-fragments
  float* xb    = (float*)(ws + 26132480);                   // N*64 f32
  float* ab1   = (float*)(ws + 32532480);                   // N*8 f32
  float* ab2   = (float*)(ws + 33332480);                   // N*8 f32
  float* xj_ws = (float*)(ws + 34132480);                   // E_PAD*64 f32
  float* al_ws = (float*)(ws + 59740672);                   // E_PAD*8 f32
  unsigned* mk = (unsigned*)(ws + 62941696);                // N*8 u32
  float* s_sum = (float*)(ws + 63741696);                   // N*8 f32

  k_h    <<<E_PAD * 16 / 256, 256, 0, stream>>>(ef, W1, b1, h_bf);
  k_w2pk <<<128, 256, 0, stream>>>(W2, w2pk);
  k_xb   <<<N_NODES * 64 / 256, 256, 0, stream>>>(x, b2, xb);
  k_ab   <<<(N_NODES * 8 + 255) / 256, 256, 0, stream>>>(xb, att, ab1, ab2);
  k_init <<<(N_NODES * 8 + 255) / 256, 256, 0, stream>>>(mk, s_sum);
  k_main <<<E_PAD / 64, 256, 0, stream>>>(x, eidx, att, ab1, ab2, h_bf, w2pk, xj_ws, al_ws, mk);
  k_exp  <<<N_EDGES * 8 / 256, 256, 0, stream>>>(al_ws, eidx, mk, s_sum);
  k_root <<<N_NODES * 64 / 256, 256, 0, stream>>>(x, root, bias, out);
  k_scatter<<<N_EDGES * 64 / 256, 256, 0, stream>>>(xj_ws, xb, al_ws, s_sum, eidx, bias, out);
  k_elu  <<<N_NODES * 64 / 256, 256, 0, stream>>>(out);
}